// Round 5
// baseline (2768.054 us; speedup 1.0000x reference)
//
#include <hip/hip_runtime.h>
#include <hip/hip_bf16.h>
#include <math.h>

// ---------------------------------------------------------------------------
// GCN 2-layer. A_hat = D^-1/2 (A+I) D^-1/2 factored: scale GEMM rows by dinv
// (epilogue), gather-sum neighbors, scale by dinv[dst], add self term.
// Round 5:
//   - hist+fill -> single-pass wave-ballot partition into 8 dst-ranges
//     (degree histogram fused), then XCD-confined scatter per range.
//   - a1 stored bf16; gemm2 rewritten LDS-free (scalar-cached W2 reads).
// ---------------------------------------------------------------------------

#define FEAT1 512
#define FEAT2 128
#define FEAT3 40

typedef __attribute__((ext_vector_type(8))) short bf16x8;
typedef __attribute__((ext_vector_type(4))) float f32x4;

__device__ __forceinline__ unsigned short f2bf(float f) {
    union { float f; unsigned u; } c; c.f = f;
    unsigned r = c.u + 0x7fff + ((c.u >> 16) & 1);   // round-nearest-even
    return (unsigned short)(r >> 16);
}
__device__ __forceinline__ float bf2f(unsigned v16) {
    union { unsigned u; float f; } c; c.u = v16 << 16;
    return c.f;
}

// ---- edge_index may be int32 (JAX default) or int64. -----------------------
__global__ void detect_i64_kernel(const int* __restrict__ ei, int* flagp) {
    __shared__ int any;
    if (threadIdx.x == 0) any = 0;
    __syncthreads();
    int v = ei[2 * threadIdx.x + 1];
    if (v != 0) any = 1;
    __syncthreads();
    if (threadIdx.x == 0) *flagp = (any == 0) ? 1 : 0;   // 1 => int64 layout
}

__device__ __forceinline__ int load_src(const int* ei, long e, long E, int f64) {
    return f64 ? ei[2 * e] : ei[e];
}
__device__ __forceinline__ int load_dst(const int* ei, long e, long E, int f64) {
    return f64 ? ei[2 * E + 2 * e] : ei[E + e];
}

// ---- Phase 1: partition edges into 8 dst-ranges + fused degree histogram ----
// Wave processes 64 contiguous edges; 8 ballots classify; lane r bulk-claims
// slots in part[r] with one atomicAdd; lanes write (src,dst) pairs contiguous.
__global__ void part_kernel(const int* __restrict__ ei, const int* __restrict__ flagp,
                            int* __restrict__ counts, int* __restrict__ pcur,
                            int2* __restrict__ part, long partCap,
                            long E, float inv8) {
    int f64 = *flagp;
    int lane = threadIdx.x & 63;
    long gw = (long)blockIdx.x * (blockDim.x >> 6) + (threadIdx.x >> 6);
    long nw = (long)gridDim.x * (blockDim.x >> 6);
    for (long base = gw * 64; base < E; base += nw * 64) {
        long e = base + lane;
        bool valid = e < E;
        int src = 0, dst = 0, myr = 8;
        if (valid) {
            src = load_src(ei, e, E, f64);
            dst = load_dst(ei, e, E, f64);
            atomicAdd(&counts[dst], 1);
            myr = (int)((float)dst * inv8);
            myr = myr > 7 ? 7 : myr;
        }
        unsigned long long mym = 0;
        int mybase = 0;
        #pragma unroll
        for (int r = 0; r < 8; r++) {
            unsigned long long mr = __ballot(valid && myr == r);
            int cnt = __popcll(mr);
            int b = 0;
            if (lane == r && cnt) b = atomicAdd(&pcur[r], cnt);
            b = __shfl(b, r);
            if (myr == r) { mym = mr; mybase = b; }
        }
        if (valid) {
            int rank = __popcll(mym & ((1ull << lane) - 1));
            part[(long)myr * partCap + mybase + rank] = make_int2(src, dst);
        }
    }
}

__global__ void scan_block_kernel(const int* __restrict__ in, int* __restrict__ excl,
                                  int* __restrict__ bsums, int N) {
    __shared__ int s[256];
    int t = threadIdx.x;
    int gid = blockIdx.x * 256 + t;
    int v = (gid < N) ? in[gid] : 0;
    s[t] = v;
    __syncthreads();
    #pragma unroll
    for (int d = 1; d < 256; d <<= 1) {
        int tv = (t >= d) ? s[t - d] : 0;
        __syncthreads();
        s[t] += tv;
        __syncthreads();
    }
    if (gid < N) excl[gid] = s[t] - v;
    if (t == 255 && bsums) bsums[blockIdx.x] = s[255];
}

__global__ void scan_finalize_kernel(const int* __restrict__ counts, int* __restrict__ off,
                                     const int* __restrict__ bsums, int* __restrict__ cursor,
                                     float* __restrict__ dinv, int N, int E) {
    int gid = blockIdx.x * 256 + threadIdx.x;
    if (gid < N) {
        int o = off[gid] + bsums[blockIdx.x];
        off[gid] = o;
        cursor[gid] = o;
        dinv[gid] = 1.0f / sqrtf((float)(counts[gid] + 1));
    }
    if (gid == 0) off[N] = E;
}

// ---- Phase 2: XCD-confined scatter; range r = blockIdx&7 --------------------
__global__ void scatter_kernel(const int2* __restrict__ part, long partCap,
                               const int* __restrict__ pcur, int* __restrict__ cursor,
                               int* __restrict__ col) {
    int r = blockIdx.x & 7;
    int n = pcur[r];
    const int2* p = part + (long)r * partCap;
    int i = (blockIdx.x >> 3) * blockDim.x + threadIdx.x;
    int stride = (gridDim.x >> 3) * blockDim.x;
    for (; i < n; i += stride) {
        int2 sd = p[i];
        int pos = atomicAdd(&cursor[sd.y], 1);
        col[pos] = sd.x;
    }
}

// ---- W1 [512,128] f32 -> Bt [128][512] bf16 (n-major, k-contiguous) --------
__global__ void w1bt_kernel(const float* __restrict__ W1, unsigned short* __restrict__ Bt) {
    int n = blockIdx.x;
    for (int k = threadIdx.x; k < FEAT1; k += blockDim.x)
        Bt[(long)n * FEAT1 + k] = f2bf(W1[(long)k * FEAT2 + n]);
}

// ---- GEMM1 (MFMA): [M,512]f32 x Bt[128][512]bf16 -> h1s bf16, *dinv[row] ---
__launch_bounds__(256)
__global__ void gemm1_mfma_kernel(const float* __restrict__ A,
                                  const unsigned short* __restrict__ Bt,
                                  const float* __restrict__ dinv,
                                  unsigned short* __restrict__ C, int M) {
    __shared__ uint4 Asm[256];          // 64 rows x 32 k bf16, fragment order
    int t = threadIdx.x;
    int m0 = blockIdx.x * 64;
    int w = t >> 6, lane = t & 63;
    int wr = w >> 1, wc = w & 1;
    int quad = lane >> 4, r15 = lane & 15;

    f32x4 acc[2][4];
    #pragma unroll
    for (int mt = 0; mt < 2; mt++)
        #pragma unroll
        for (int nt = 0; nt < 4; nt++) acc[mt][nt] = (f32x4){0.f, 0.f, 0.f, 0.f};

    for (int k0 = 0; k0 < FEAT1; k0 += 32) {
        __syncthreads();
        #pragma unroll
        for (int i = 0; i < 2; i++) {
            int id = t + i * 256;
            int row = id >> 3, q = id & 7;
            int grow = m0 + row;
            float4 v = make_float4(0.f, 0.f, 0.f, 0.f);
            if (grow < M) v = *(const float4*)(A + (long)grow * FEAT1 + k0 + q * 4);
            uint2 p;
            p.x = (unsigned)f2bf(v.x) | ((unsigned)f2bf(v.y) << 16);
            p.y = (unsigned)f2bf(v.z) | ((unsigned)f2bf(v.w) << 16);
            ((uint2*)Asm)[(row >> 4) * 128 + (((row & 15) + ((q >> 1) << 4)) << 1) + (q & 1)] = p;
        }
        __syncthreads();

        bf16x8 af[2];
        #pragma unroll
        for (int mt = 0; mt < 2; mt++)
            af[mt] = ((const bf16x8*)Asm)[(wr * 2 + mt) * 64 + lane];

        #pragma unroll
        for (int nt = 0; nt < 4; nt++) {
            bf16x8 bf = *(const bf16x8*)(Bt + (long)(wc * 64 + nt * 16 + r15) * FEAT1 + k0 + quad * 8);
            acc[0][nt] = __builtin_amdgcn_mfma_f32_16x16x32_bf16(af[0], bf, acc[0][nt], 0, 0, 0);
            acc[1][nt] = __builtin_amdgcn_mfma_f32_16x16x32_bf16(af[1], bf, acc[1][nt], 0, 0, 0);
        }
    }

    #pragma unroll
    for (int mt = 0; mt < 2; mt++) {
        int rb = m0 + wr * 32 + mt * 16 + quad * 4;
        #pragma unroll
        for (int reg = 0; reg < 4; reg++) {
            int row = rb + reg;
            if (row >= M) continue;
            float di = dinv[row];
            #pragma unroll
            for (int nt = 0; nt < 4; nt++) {
                C[(long)row * FEAT2 + wc * 64 + nt * 16 + r15] = f2bf(acc[mt][nt][reg] * di);
            }
        }
    }
}

// ---- Aggregation 1: wave-per-node; shfl-broadcast col; writes bf16 a1 -------
__launch_bounds__(256)
__global__ void agg1_kernel(const unsigned short* __restrict__ h1s,
                            const int* __restrict__ col, const int* __restrict__ off,
                            const float* __restrict__ dinv, const float* __restrict__ b1,
                            unsigned short* __restrict__ a1, int N) {
    int node = blockIdx.x * 4 + (threadIdx.x >> 6);
    if (node >= N) return;
    int l = threadIdx.x & 63;            // lane handles feats 2l, 2l+1
    int o0 = off[node], o1 = off[node + 1];
    float ax = 0.f, ay = 0.f;
    for (int base = o0; base < o1; base += 64) {
        int cnt = min(64, o1 - base);
        int myc = (l < cnt) ? col[base + l] : 0;
        int e = 0;
        for (; e + 4 <= cnt; e += 4) {
            int s0 = __shfl(myc, e + 0);
            int s1 = __shfl(myc, e + 1);
            int s2 = __shfl(myc, e + 2);
            int s3 = __shfl(myc, e + 3);
            unsigned p0 = *(const unsigned*)(h1s + (long)s0 * FEAT2 + 2 * l);
            unsigned p1 = *(const unsigned*)(h1s + (long)s1 * FEAT2 + 2 * l);
            unsigned p2 = *(const unsigned*)(h1s + (long)s2 * FEAT2 + 2 * l);
            unsigned p3 = *(const unsigned*)(h1s + (long)s3 * FEAT2 + 2 * l);
            ax += bf2f(p0 & 0xffffu) + bf2f(p1 & 0xffffu) +
                  bf2f(p2 & 0xffffu) + bf2f(p3 & 0xffffu);
            ay += bf2f(p0 >> 16) + bf2f(p1 >> 16) + bf2f(p2 >> 16) + bf2f(p3 >> 16);
        }
        for (; e < cnt; ++e) {
            int s = __shfl(myc, e);
            unsigned p = *(const unsigned*)(h1s + (long)s * FEAT2 + 2 * l);
            ax += bf2f(p & 0xffffu);
            ay += bf2f(p >> 16);
        }
    }
    unsigned pv = *(const unsigned*)(h1s + (long)node * FEAT2 + 2 * l);  // self
    ax += bf2f(pv & 0xffffu);
    ay += bf2f(pv >> 16);
    float di = dinv[node];
    float2 b = *(const float2*)(b1 + 2 * l);
    float vx = ax * di + b.x;
    float vy = ay * di + b.y;
    vx = vx > 0.f ? vx : 0.f;
    vy = vy > 0.f ? vy : 0.f;
    *(unsigned*)(a1 + (long)node * FEAT2 + 2 * l) =
        (unsigned)f2bf(vx) | ((unsigned)f2bf(vy) << 16);
}

// ---- GEMM2: [M,128]bf16 @ [128,40]f32, node-per-thread, LDS-free ------------
// W reads are wave-uniform -> compiler scalarizes to s_load (20KB hot in sL1).
__launch_bounds__(256)
__global__ void gemm2_kernel(const unsigned short* __restrict__ A,
                             const float* __restrict__ W,
                             const float* __restrict__ dinv,
                             unsigned short* __restrict__ C, int M) {
    int node = blockIdx.x * 256 + threadIdx.x;
    if (node >= M) return;
    const uint4* ap = (const uint4*)(A + (long)node * FEAT2);
    float acc[FEAT3];
    #pragma unroll
    for (int j = 0; j < FEAT3; j++) acc[j] = 0.f;
    #pragma unroll
    for (int c = 0; c < FEAT2 / 8; c++) {      // 16 chunks of 8 bf16
        uint4 v = ap[c];
        unsigned vv[4] = {v.x, v.y, v.z, v.w};
        #pragma unroll
        for (int q = 0; q < 4; q++) {
            float a0 = bf2f(vv[q] & 0xffffu);
            float a1v = bf2f(vv[q] >> 16);
            int k = c * 8 + q * 2;
            #pragma unroll
            for (int j = 0; j < FEAT3; j++)
                acc[j] += a0 * W[k * FEAT3 + j] + a1v * W[(k + 1) * FEAT3 + j];
        }
    }
    float di = dinv[node];
    unsigned* cp = (unsigned*)(C + (long)node * FEAT3);
    #pragma unroll
    for (int j = 0; j < FEAT3 / 2; j++) {
        cp[j] = (unsigned)f2bf(acc[2 * j] * di) |
                ((unsigned)f2bf(acc[2 * j + 1] * di) << 16);
    }
}

// ---- Aggregation 2 + log_softmax: wave-per-node, shfl col, 4-way unroll -----
__launch_bounds__(256)
__global__ void agg2_lsm_kernel(const unsigned short* __restrict__ h2s,
                                const int* __restrict__ col, const int* __restrict__ off,
                                const float* __restrict__ dinv, const float* __restrict__ b2,
                                float* __restrict__ out, int N) {
    int node = blockIdx.x * 4 + (threadIdx.x >> 6);
    if (node >= N) return;
    int l = threadIdx.x & 63;
    bool act = l < FEAT3 / 2;
    int o0 = off[node], o1 = off[node + 1];
    float ax = 0.f, ay = 0.f;
    for (int base = o0; base < o1; base += 64) {
        int cnt = min(64, o1 - base);
        int myc = (l < cnt) ? col[base + l] : 0;
        int e = 0;
        for (; e + 4 <= cnt; e += 4) {
            int s0 = __shfl(myc, e + 0);
            int s1 = __shfl(myc, e + 1);
            int s2 = __shfl(myc, e + 2);
            int s3 = __shfl(myc, e + 3);
            if (act) {
                unsigned p0 = *(const unsigned*)(h2s + (long)s0 * FEAT3 + 2 * l);
                unsigned p1 = *(const unsigned*)(h2s + (long)s1 * FEAT3 + 2 * l);
                unsigned p2 = *(const unsigned*)(h2s + (long)s2 * FEAT3 + 2 * l);
                unsigned p3 = *(const unsigned*)(h2s + (long)s3 * FEAT3 + 2 * l);
                ax += bf2f(p0 & 0xffffu) + bf2f(p1 & 0xffffu) +
                      bf2f(p2 & 0xffffu) + bf2f(p3 & 0xffffu);
                ay += bf2f(p0 >> 16) + bf2f(p1 >> 16) + bf2f(p2 >> 16) + bf2f(p3 >> 16);
            }
        }
        for (; e < cnt; ++e) {
            int s = __shfl(myc, e);
            if (act) {
                unsigned p = *(const unsigned*)(h2s + (long)s * FEAT3 + 2 * l);
                ax += bf2f(p & 0xffffu);
                ay += bf2f(p >> 16);
            }
        }
    }
    float vx = -INFINITY, vy = -INFINITY;
    if (act) {
        unsigned pv = *(const unsigned*)(h2s + (long)node * FEAT3 + 2 * l);  // self
        float di = dinv[node];
        float2 b = *(const float2*)(b2 + 2 * l);
        vx = (ax + bf2f(pv & 0xffffu)) * di + b.x;
        vy = (ay + bf2f(pv >> 16)) * di + b.y;
    }
    float m = fmaxf(vx, vy);
    #pragma unroll
    for (int o = 32; o >= 1; o >>= 1) m = fmaxf(m, __shfl_xor(m, o));
    float e = act ? (expf(vx - m) + expf(vy - m)) : 0.f;
    #pragma unroll
    for (int o = 32; o >= 1; o >>= 1) e += __shfl_xor(e, o);
    float ls = logf(e);
    if (act) {
        *(float2*)(out + (long)node * FEAT3 + 2 * l) = make_float2(vx - m - ls, vy - m - ls);
    }
}

// ---------------------------------------------------------------------------
extern "C" void kernel_launch(void* const* d_in, const int* in_sizes, int n_in,
                              void* d_out, int out_size, void* d_ws, size_t ws_size,
                              hipStream_t stream) {
    const float* x  = (const float*)d_in[0];
    const int*   ei = (const int*)d_in[1];
    const float* W1 = (const float*)d_in[2];
    const float* b1 = (const float*)d_in[3];
    const float* W2 = (const float*)d_in[4];
    const float* b2 = (const float*)d_in[5];
    float* out = (float*)d_out;

    const int  N = in_sizes[0] / FEAT1;       // 50000
    const long E = in_sizes[1] / 2;           // 1600000

    char* ws = (char*)d_ws;
    size_t off = 0;
    auto alloc = [&](size_t bytes) -> void* {
        off = (off + 255) & ~(size_t)255;
        void* p = ws + off;
        off += bytes;
        return p;
    };
    const long partCap = E / 8 + 65536;       // mean E/8, slack >>5 sigma
    int*   counts  = (int*)alloc((size_t)N * 4);
    int*   offsets = (int*)alloc((size_t)(N + 1) * 4);
    int*   cursor  = (int*)alloc((size_t)N * 4);
    float* dinv    = (float*)alloc((size_t)N * 4);
    int*   col     = (int*)alloc((size_t)E * 4);
    unsigned short* h1s = (unsigned short*)alloc((size_t)N * FEAT2 * 2);
    unsigned short* a1  = (unsigned short*)alloc((size_t)N * FEAT2 * 2);
    unsigned short* h2s = (unsigned short*)alloc((size_t)N * FEAT3 * 2);
    unsigned short* Bt  = (unsigned short*)alloc((size_t)FEAT2 * FEAT1 * 2);
    int2*  part    = (int2*)alloc((size_t)8 * partCap * 8);
    int*   pcur    = (int*)alloc(8 * 4);
    int*   bsums   = (int*)alloc(256 * 4);
    int*   flagp   = (int*)alloc(4);

    const int nb = (N + 255) / 256;

    detect_i64_kernel<<<1, 256, 0, stream>>>(ei, flagp);
    hipMemsetAsync(counts, 0, (size_t)N * 4, stream);
    hipMemsetAsync(pcur, 0, 8 * 4, stream);
    part_kernel<<<2048, 256, 0, stream>>>(ei, flagp, counts, pcur, part, partCap,
                                          E, 8.0f / (float)N);
    scan_block_kernel<<<nb, 256, 0, stream>>>(counts, offsets, bsums, N);
    scan_block_kernel<<<1, 256, 0, stream>>>(bsums, bsums, nullptr, nb);
    scan_finalize_kernel<<<nb, 256, 0, stream>>>(counts, offsets, bsums, cursor, dinv, N, (int)E);
    scatter_kernel<<<2048, 256, 0, stream>>>(part, partCap, pcur, cursor, col);

    w1bt_kernel<<<FEAT2, 256, 0, stream>>>(W1, Bt);
    gemm1_mfma_kernel<<<(N + 63) / 64, 256, 0, stream>>>(x, Bt, dinv, h1s, N);
    agg1_kernel<<<(N + 3) / 4, 256, 0, stream>>>(h1s, col, offsets, dinv, b1, a1, N);
    gemm2_kernel<<<(N + 255) / 256, 256, 0, stream>>>(a1, W2, dinv, h2s, N);
    agg2_lsm_kernel<<<(N + 3) / 4, 256, 0, stream>>>(h2s, col, offsets, dinv, b2, out, N);
}

// Round 6
// 574.319 us; speedup vs baseline: 4.8197x; 4.8197x over previous
//
#include <hip/hip_runtime.h>
#include <hip/hip_bf16.h>
#include <math.h>

// ---------------------------------------------------------------------------
// GCN 2-layer. A_hat = D^-1/2 (A+I) D^-1/2 factored: scale GEMM rows by dinv
// (epilogue), gather-sum neighbors, scale by dinv[dst], add self term.
// Round 6: part_kernel rebuilt as block-level two-pass partition.
//   R5 bug: 200k global atomics on 8 counters in ONE cache line -> 11ns-serial
//   chain = 2276us. Now: LDS allocators per block, ONE global claim per
//   range per block on line-padded counters (256 blocks -> 2k atomics total).
// ---------------------------------------------------------------------------

#define FEAT1 512
#define FEAT2 128
#define FEAT3 40
#define PCUR_STRIDE 32   // pad allocator counters to separate 128B lines

typedef __attribute__((ext_vector_type(8))) short bf16x8;
typedef __attribute__((ext_vector_type(4))) float f32x4;

__device__ __forceinline__ unsigned short f2bf(float f) {
    union { float f; unsigned u; } c; c.f = f;
    unsigned r = c.u + 0x7fff + ((c.u >> 16) & 1);   // round-nearest-even
    return (unsigned short)(r >> 16);
}
__device__ __forceinline__ float bf2f(unsigned v16) {
    union { unsigned u; float f; } c; c.u = v16 << 16;
    return c.f;
}

// ---- edge_index may be int32 (JAX default) or int64. -----------------------
__global__ void detect_i64_kernel(const int* __restrict__ ei, int* flagp) {
    __shared__ int any;
    if (threadIdx.x == 0) any = 0;
    __syncthreads();
    int v = ei[2 * threadIdx.x + 1];
    if (v != 0) any = 1;
    __syncthreads();
    if (threadIdx.x == 0) *flagp = (any == 0) ? 1 : 0;   // 1 => int64 layout
}

__device__ __forceinline__ int load_src(const int* ei, long e, long E, int f64) {
    return f64 ? ei[2 * e] : ei[e];
}
__device__ __forceinline__ int load_dst(const int* ei, long e, long E, int f64) {
    return f64 ? ei[2 * E + 2 * e] : ei[E + e];
}

// ---- Partition: block-level two-pass; fused degree histogram ---------------
// Block owns contiguous chunk. Pass1: counts[] atomics + LDS range-hist
// (wave-ballot aggregated). Claim: 1 global atomic per range per block on
// padded pcur. Pass2: wave-ballot rank + LDS cursor, contiguous part writes.
__launch_bounds__(1024)
__global__ void part_kernel(const int* __restrict__ ei, const int* __restrict__ flagp,
                            int* __restrict__ counts, int* __restrict__ pcur,
                            int2* __restrict__ part, long partCap,
                            long E, float inv8) {
    __shared__ int lhist[8], lbase[8], lcur[8];
    int f64 = *flagp;
    int t = threadIdx.x;
    int lane = t & 63;
    long chunk = (E + gridDim.x - 1) / gridDim.x;
    long start = (long)blockIdx.x * chunk;
    long end = start + chunk; if (end > E) end = E;
    if (t < 8) { lhist[t] = 0; lcur[t] = 0; }
    __syncthreads();

    // pass 1
    for (long e0 = start; e0 < end; e0 += blockDim.x) {
        long e = e0 + t;
        bool valid = e < end;
        int myr = 8;
        if (valid) {
            int dst = load_dst(ei, e, E, f64);
            atomicAdd(&counts[dst], 1);
            myr = (int)((float)dst * inv8);
            myr = myr > 7 ? 7 : myr;
        }
        #pragma unroll
        for (int r = 0; r < 8; r++) {
            unsigned long long mr = __ballot(myr == r);
            int cnt = __popcll(mr);
            if (lane == r && cnt) atomicAdd(&lhist[r], cnt);
        }
    }
    __syncthreads();
    if (t < 8) lbase[t] = atomicAdd(&pcur[t * PCUR_STRIDE], lhist[t]);
    __syncthreads();

    // pass 2 (chunk re-read is L2-warm)
    for (long e0 = start; e0 < end; e0 += blockDim.x) {
        long e = e0 + t;
        bool valid = e < end;
        int src = 0, dst = 0, myr = 8;
        if (valid) {
            src = load_src(ei, e, E, f64);
            dst = load_dst(ei, e, E, f64);
            myr = (int)((float)dst * inv8);
            myr = myr > 7 ? 7 : myr;
        }
        unsigned long long mym = 0;
        int mypos = 0;
        #pragma unroll
        for (int r = 0; r < 8; r++) {
            unsigned long long mr = __ballot(myr == r);
            int cnt = __popcll(mr);
            int b = 0;
            if (lane == r && cnt) b = atomicAdd(&lcur[r], cnt);   // LDS alloc
            b = __shfl(b, r);
            if (myr == r) { mym = mr; mypos = b; }
        }
        if (valid) {
            int rank = __popcll(mym & ((1ull << lane) - 1));
            part[(long)myr * partCap + lbase[myr] + mypos + rank] = make_int2(src, dst);
        }
    }
}

__global__ void scan_block_kernel(const int* __restrict__ in, int* __restrict__ excl,
                                  int* __restrict__ bsums, int N) {
    __shared__ int s[256];
    int t = threadIdx.x;
    int gid = blockIdx.x * 256 + t;
    int v = (gid < N) ? in[gid] : 0;
    s[t] = v;
    __syncthreads();
    #pragma unroll
    for (int d = 1; d < 256; d <<= 1) {
        int tv = (t >= d) ? s[t - d] : 0;
        __syncthreads();
        s[t] += tv;
        __syncthreads();
    }
    if (gid < N) excl[gid] = s[t] - v;
    if (t == 255 && bsums) bsums[blockIdx.x] = s[255];
}

__global__ void scan_finalize_kernel(const int* __restrict__ counts, int* __restrict__ off,
                                     const int* __restrict__ bsums, int* __restrict__ cursor,
                                     float* __restrict__ dinv, int N, int E) {
    int gid = blockIdx.x * 256 + threadIdx.x;
    if (gid < N) {
        int o = off[gid] + bsums[blockIdx.x];
        off[gid] = o;
        cursor[gid] = o;
        dinv[gid] = 1.0f / sqrtf((float)(counts[gid] + 1));
    }
    if (gid == 0) off[N] = E;
}

// ---- Scatter: XCD-confined; range r = blockIdx&7 ---------------------------
__global__ void scatter_kernel(const int2* __restrict__ part, long partCap,
                               const int* __restrict__ pcur, int* __restrict__ cursor,
                               int* __restrict__ col) {
    int r = blockIdx.x & 7;
    int n = pcur[r * PCUR_STRIDE];
    const int2* p = part + (long)r * partCap;
    int i = (blockIdx.x >> 3) * blockDim.x + threadIdx.x;
    int stride = (gridDim.x >> 3) * blockDim.x;
    for (; i < n; i += stride) {
        int2 sd = p[i];
        int pos = atomicAdd(&cursor[sd.y], 1);
        col[pos] = sd.x;
    }
}

// ---- W1 [512,128] f32 -> Bt [128][512] bf16 (n-major, k-contiguous) --------
__global__ void w1bt_kernel(const float* __restrict__ W1, unsigned short* __restrict__ Bt) {
    int n = blockIdx.x;
    for (int k = threadIdx.x; k < FEAT1; k += blockDim.x)
        Bt[(long)n * FEAT1 + k] = f2bf(W1[(long)k * FEAT2 + n]);
}

// ---- GEMM1 (MFMA): [M,512]f32 x Bt[128][512]bf16 -> h1s bf16, *dinv[row] ---
__launch_bounds__(256)
__global__ void gemm1_mfma_kernel(const float* __restrict__ A,
                                  const unsigned short* __restrict__ Bt,
                                  const float* __restrict__ dinv,
                                  unsigned short* __restrict__ C, int M) {
    __shared__ uint4 Asm[256];          // 64 rows x 32 k bf16, fragment order
    int t = threadIdx.x;
    int m0 = blockIdx.x * 64;
    int w = t >> 6, lane = t & 63;
    int wr = w >> 1, wc = w & 1;
    int quad = lane >> 4, r15 = lane & 15;

    f32x4 acc[2][4];
    #pragma unroll
    for (int mt = 0; mt < 2; mt++)
        #pragma unroll
        for (int nt = 0; nt < 4; nt++) acc[mt][nt] = (f32x4){0.f, 0.f, 0.f, 0.f};

    for (int k0 = 0; k0 < FEAT1; k0 += 32) {
        __syncthreads();
        #pragma unroll
        for (int i = 0; i < 2; i++) {
            int id = t + i * 256;
            int row = id >> 3, q = id & 7;
            int grow = m0 + row;
            float4 v = make_float4(0.f, 0.f, 0.f, 0.f);
            if (grow < M) v = *(const float4*)(A + (long)grow * FEAT1 + k0 + q * 4);
            uint2 p;
            p.x = (unsigned)f2bf(v.x) | ((unsigned)f2bf(v.y) << 16);
            p.y = (unsigned)f2bf(v.z) | ((unsigned)f2bf(v.w) << 16);
            ((uint2*)Asm)[(row >> 4) * 128 + (((row & 15) + ((q >> 1) << 4)) << 1) + (q & 1)] = p;
        }
        __syncthreads();

        bf16x8 af[2];
        #pragma unroll
        for (int mt = 0; mt < 2; mt++)
            af[mt] = ((const bf16x8*)Asm)[(wr * 2 + mt) * 64 + lane];

        #pragma unroll
        for (int nt = 0; nt < 4; nt++) {
            bf16x8 bf = *(const bf16x8*)(Bt + (long)(wc * 64 + nt * 16 + r15) * FEAT1 + k0 + quad * 8);
            acc[0][nt] = __builtin_amdgcn_mfma_f32_16x16x32_bf16(af[0], bf, acc[0][nt], 0, 0, 0);
            acc[1][nt] = __builtin_amdgcn_mfma_f32_16x16x32_bf16(af[1], bf, acc[1][nt], 0, 0, 0);
        }
    }

    #pragma unroll
    for (int mt = 0; mt < 2; mt++) {
        int rb = m0 + wr * 32 + mt * 16 + quad * 4;
        #pragma unroll
        for (int reg = 0; reg < 4; reg++) {
            int row = rb + reg;
            if (row >= M) continue;
            float di = dinv[row];
            #pragma unroll
            for (int nt = 0; nt < 4; nt++) {
                C[(long)row * FEAT2 + wc * 64 + nt * 16 + r15] = f2bf(acc[mt][nt][reg] * di);
            }
        }
    }
}

// ---- Aggregation 1: wave-per-node; shfl-broadcast col; writes bf16 a1 -------
__launch_bounds__(256)
__global__ void agg1_kernel(const unsigned short* __restrict__ h1s,
                            const int* __restrict__ col, const int* __restrict__ off,
                            const float* __restrict__ dinv, const float* __restrict__ b1,
                            unsigned short* __restrict__ a1, int N) {
    int node = blockIdx.x * 4 + (threadIdx.x >> 6);
    if (node >= N) return;
    int l = threadIdx.x & 63;            // lane handles feats 2l, 2l+1
    int o0 = off[node], o1 = off[node + 1];
    float ax = 0.f, ay = 0.f;
    for (int base = o0; base < o1; base += 64) {
        int cnt = min(64, o1 - base);
        int myc = (l < cnt) ? col[base + l] : 0;
        int e = 0;
        for (; e + 4 <= cnt; e += 4) {
            int s0 = __shfl(myc, e + 0);
            int s1 = __shfl(myc, e + 1);
            int s2 = __shfl(myc, e + 2);
            int s3 = __shfl(myc, e + 3);
            unsigned p0 = *(const unsigned*)(h1s + (long)s0 * FEAT2 + 2 * l);
            unsigned p1 = *(const unsigned*)(h1s + (long)s1 * FEAT2 + 2 * l);
            unsigned p2 = *(const unsigned*)(h1s + (long)s2 * FEAT2 + 2 * l);
            unsigned p3 = *(const unsigned*)(h1s + (long)s3 * FEAT2 + 2 * l);
            ax += bf2f(p0 & 0xffffu) + bf2f(p1 & 0xffffu) +
                  bf2f(p2 & 0xffffu) + bf2f(p3 & 0xffffu);
            ay += bf2f(p0 >> 16) + bf2f(p1 >> 16) + bf2f(p2 >> 16) + bf2f(p3 >> 16);
        }
        for (; e < cnt; ++e) {
            int s = __shfl(myc, e);
            unsigned p = *(const unsigned*)(h1s + (long)s * FEAT2 + 2 * l);
            ax += bf2f(p & 0xffffu);
            ay += bf2f(p >> 16);
        }
    }
    unsigned pv = *(const unsigned*)(h1s + (long)node * FEAT2 + 2 * l);  // self
    ax += bf2f(pv & 0xffffu);
    ay += bf2f(pv >> 16);
    float di = dinv[node];
    float2 b = *(const float2*)(b1 + 2 * l);
    float vx = ax * di + b.x;
    float vy = ay * di + b.y;
    vx = vx > 0.f ? vx : 0.f;
    vy = vy > 0.f ? vy : 0.f;
    *(unsigned*)(a1 + (long)node * FEAT2 + 2 * l) =
        (unsigned)f2bf(vx) | ((unsigned)f2bf(vy) << 16);
}

// ---- GEMM2: [M,128]bf16 @ [128,40]f32, node-per-thread, LDS-free ------------
__launch_bounds__(256)
__global__ void gemm2_kernel(const unsigned short* __restrict__ A,
                             const float* __restrict__ W,
                             const float* __restrict__ dinv,
                             unsigned short* __restrict__ C, int M) {
    int node = blockIdx.x * 256 + threadIdx.x;
    if (node >= M) return;
    const uint4* ap = (const uint4*)(A + (long)node * FEAT2);
    float acc[FEAT3];
    #pragma unroll
    for (int j = 0; j < FEAT3; j++) acc[j] = 0.f;
    #pragma unroll
    for (int c = 0; c < FEAT2 / 8; c++) {      // 16 chunks of 8 bf16
        uint4 v = ap[c];
        unsigned vv[4] = {v.x, v.y, v.z, v.w};
        #pragma unroll
        for (int q = 0; q < 4; q++) {
            float a0 = bf2f(vv[q] & 0xffffu);
            float a1v = bf2f(vv[q] >> 16);
            int k = c * 8 + q * 2;
            #pragma unroll
            for (int j = 0; j < FEAT3; j++)
                acc[j] += a0 * W[k * FEAT3 + j] + a1v * W[(k + 1) * FEAT3 + j];
        }
    }
    float di = dinv[node];
    unsigned* cp = (unsigned*)(C + (long)node * FEAT3);
    #pragma unroll
    for (int j = 0; j < FEAT3 / 2; j++) {
        cp[j] = (unsigned)f2bf(acc[2 * j] * di) |
                ((unsigned)f2bf(acc[2 * j + 1] * di) << 16);
    }
}

// ---- Aggregation 2 + log_softmax: wave-per-node, shfl col, 4-way unroll -----
__launch_bounds__(256)
__global__ void agg2_lsm_kernel(const unsigned short* __restrict__ h2s,
                                const int* __restrict__ col, const int* __restrict__ off,
                                const float* __restrict__ dinv, const float* __restrict__ b2,
                                float* __restrict__ out, int N) {
    int node = blockIdx.x * 4 + (threadIdx.x >> 6);
    if (node >= N) return;
    int l = threadIdx.x & 63;
    bool act = l < FEAT3 / 2;
    int o0 = off[node], o1 = off[node + 1];
    float ax = 0.f, ay = 0.f;
    for (int base = o0; base < o1; base += 64) {
        int cnt = min(64, o1 - base);
        int myc = (l < cnt) ? col[base + l] : 0;
        int e = 0;
        for (; e + 4 <= cnt; e += 4) {
            int s0 = __shfl(myc, e + 0);
            int s1 = __shfl(myc, e + 1);
            int s2 = __shfl(myc, e + 2);
            int s3 = __shfl(myc, e + 3);
            if (act) {
                unsigned p0 = *(const unsigned*)(h2s + (long)s0 * FEAT3 + 2 * l);
                unsigned p1 = *(const unsigned*)(h2s + (long)s1 * FEAT3 + 2 * l);
                unsigned p2 = *(const unsigned*)(h2s + (long)s2 * FEAT3 + 2 * l);
                unsigned p3 = *(const unsigned*)(h2s + (long)s3 * FEAT3 + 2 * l);
                ax += bf2f(p0 & 0xffffu) + bf2f(p1 & 0xffffu) +
                      bf2f(p2 & 0xffffu) + bf2f(p3 & 0xffffu);
                ay += bf2f(p0 >> 16) + bf2f(p1 >> 16) + bf2f(p2 >> 16) + bf2f(p3 >> 16);
            }
        }
        for (; e < cnt; ++e) {
            int s = __shfl(myc, e);
            if (act) {
                unsigned p = *(const unsigned*)(h2s + (long)s * FEAT3 + 2 * l);
                ax += bf2f(p & 0xffffu);
                ay += bf2f(p >> 16);
            }
        }
    }
    float vx = -INFINITY, vy = -INFINITY;
    if (act) {
        unsigned pv = *(const unsigned*)(h2s + (long)node * FEAT3 + 2 * l);  // self
        float di = dinv[node];
        float2 b = *(const float2*)(b2 + 2 * l);
        vx = (ax + bf2f(pv & 0xffffu)) * di + b.x;
        vy = (ay + bf2f(pv >> 16)) * di + b.y;
    }
    float m = fmaxf(vx, vy);
    #pragma unroll
    for (int o = 32; o >= 1; o >>= 1) m = fmaxf(m, __shfl_xor(m, o));
    float e = act ? (expf(vx - m) + expf(vy - m)) : 0.f;
    #pragma unroll
    for (int o = 32; o >= 1; o >>= 1) e += __shfl_xor(e, o);
    float ls = logf(e);
    if (act) {
        *(float2*)(out + (long)node * FEAT3 + 2 * l) = make_float2(vx - m - ls, vy - m - ls);
    }
}

// ---------------------------------------------------------------------------
extern "C" void kernel_launch(void* const* d_in, const int* in_sizes, int n_in,
                              void* d_out, int out_size, void* d_ws, size_t ws_size,
                              hipStream_t stream) {
    const float* x  = (const float*)d_in[0];
    const int*   ei = (const int*)d_in[1];
    const float* W1 = (const float*)d_in[2];
    const float* b1 = (const float*)d_in[3];
    const float* W2 = (const float*)d_in[4];
    const float* b2 = (const float*)d_in[5];
    float* out = (float*)d_out;

    const int  N = in_sizes[0] / FEAT1;       // 50000
    const long E = in_sizes[1] / 2;           // 1600000

    char* ws = (char*)d_ws;
    size_t off = 0;
    auto alloc = [&](size_t bytes) -> void* {
        off = (off + 255) & ~(size_t)255;
        void* p = ws + off;
        off += bytes;
        return p;
    };
    const long partCap = E / 8 + 65536;
    int*   counts  = (int*)alloc((size_t)N * 4);
    int*   offsets = (int*)alloc((size_t)(N + 1) * 4);
    int*   cursor  = (int*)alloc((size_t)N * 4);
    float* dinv    = (float*)alloc((size_t)N * 4);
    int*   col     = (int*)alloc((size_t)E * 4);
    unsigned short* h1s = (unsigned short*)alloc((size_t)N * FEAT2 * 2);
    unsigned short* a1  = (unsigned short*)alloc((size_t)N * FEAT2 * 2);
    unsigned short* h2s = (unsigned short*)alloc((size_t)N * FEAT3 * 2);
    unsigned short* Bt  = (unsigned short*)alloc((size_t)FEAT2 * FEAT1 * 2);
    int2*  part    = (int2*)alloc((size_t)8 * partCap * 8);
    int*   pcur    = (int*)alloc(8 * PCUR_STRIDE * 4);
    int*   bsums   = (int*)alloc(256 * 4);
    int*   flagp   = (int*)alloc(4);

    const int nb = (N + 255) / 256;

    detect_i64_kernel<<<1, 256, 0, stream>>>(ei, flagp);
    hipMemsetAsync(counts, 0, (size_t)N * 4, stream);
    hipMemsetAsync(pcur, 0, (size_t)8 * PCUR_STRIDE * 4, stream);
    part_kernel<<<256, 1024, 0, stream>>>(ei, flagp, counts, pcur, part, partCap,
                                          E, 8.0f / (float)N);
    scan_block_kernel<<<nb, 256, 0, stream>>>(counts, offsets, bsums, N);
    scan_block_kernel<<<1, 256, 0, stream>>>(bsums, bsums, nullptr, nb);
    scan_finalize_kernel<<<nb, 256, 0, stream>>>(counts, offsets, bsums, cursor, dinv, N, (int)E);
    scatter_kernel<<<2048, 256, 0, stream>>>(part, partCap, pcur, cursor, col);

    w1bt_kernel<<<FEAT2, 256, 0, stream>>>(W1, Bt);
    gemm1_mfma_kernel<<<(N + 63) / 64, 256, 0, stream>>>(x, Bt, dinv, h1s, N);
    agg1_kernel<<<(N + 3) / 4, 256, 0, stream>>>(h1s, col, offsets, dinv, b1, a1, N);
    gemm2_kernel<<<(N + 255) / 256, 256, 0, stream>>>(a1, W2, dinv, h2s, N);
    agg2_lsm_kernel<<<(N + 3) / 4, 256, 0, stream>>>(h2s, col, offsets, dinv, b2, out, N);
}

// Round 7
// 458.376 us; speedup vs baseline: 6.0388x; 1.2529x over previous
//
#include <hip/hip_runtime.h>
#include <hip/hip_bf16.h>
#include <math.h>

// ---------------------------------------------------------------------------
// GCN 2-layer. A_hat = D^-1/2 (A+I) D^-1/2 factored: scale GEMM rows by dinv
// (epilogue), gather-sum neighbors, scale by dinv[dst], add self term.
// Round 7: gemm2 -> MFMA (R6's scalar-W version was latency-bound at 9%
// occupancy, 131us). One wave per 16 rows, W2 pre-transposed to bf16
// Bt2[48][128] (zero-padded), 12 mfma_16x16x32 per wave, no LDS.
// ---------------------------------------------------------------------------

#define FEAT1 512
#define FEAT2 128
#define FEAT3 40
#define PCUR_STRIDE 32   // pad allocator counters to separate 128B lines

typedef __attribute__((ext_vector_type(8))) short bf16x8;
typedef __attribute__((ext_vector_type(4))) float f32x4;

__device__ __forceinline__ unsigned short f2bf(float f) {
    union { float f; unsigned u; } c; c.f = f;
    unsigned r = c.u + 0x7fff + ((c.u >> 16) & 1);   // round-nearest-even
    return (unsigned short)(r >> 16);
}
__device__ __forceinline__ float bf2f(unsigned v16) {
    union { unsigned u; float f; } c; c.u = v16 << 16;
    return c.f;
}

// ---- edge_index may be int32 (JAX default) or int64. -----------------------
__global__ void detect_i64_kernel(const int* __restrict__ ei, int* flagp) {
    __shared__ int any;
    if (threadIdx.x == 0) any = 0;
    __syncthreads();
    int v = ei[2 * threadIdx.x + 1];
    if (v != 0) any = 1;
    __syncthreads();
    if (threadIdx.x == 0) *flagp = (any == 0) ? 1 : 0;   // 1 => int64 layout
}

__device__ __forceinline__ int load_src(const int* ei, long e, long E, int f64) {
    return f64 ? ei[2 * e] : ei[e];
}
__device__ __forceinline__ int load_dst(const int* ei, long e, long E, int f64) {
    return f64 ? ei[2 * E + 2 * e] : ei[E + e];
}

// ---- Partition: block-level two-pass; fused degree histogram ---------------
__launch_bounds__(1024)
__global__ void part_kernel(const int* __restrict__ ei, const int* __restrict__ flagp,
                            int* __restrict__ counts, int* __restrict__ pcur,
                            int2* __restrict__ part, long partCap,
                            long E, float inv8) {
    __shared__ int lhist[8], lbase[8], lcur[8];
    int f64 = *flagp;
    int t = threadIdx.x;
    int lane = t & 63;
    long chunk = (E + gridDim.x - 1) / gridDim.x;
    long start = (long)blockIdx.x * chunk;
    long end = start + chunk; if (end > E) end = E;
    if (t < 8) { lhist[t] = 0; lcur[t] = 0; }
    __syncthreads();

    // pass 1
    for (long e0 = start; e0 < end; e0 += blockDim.x) {
        long e = e0 + t;
        bool valid = e < end;
        int myr = 8;
        if (valid) {
            int dst = load_dst(ei, e, E, f64);
            atomicAdd(&counts[dst], 1);
            myr = (int)((float)dst * inv8);
            myr = myr > 7 ? 7 : myr;
        }
        #pragma unroll
        for (int r = 0; r < 8; r++) {
            unsigned long long mr = __ballot(myr == r);
            int cnt = __popcll(mr);
            if (lane == r && cnt) atomicAdd(&lhist[r], cnt);
        }
    }
    __syncthreads();
    if (t < 8) lbase[t] = atomicAdd(&pcur[t * PCUR_STRIDE], lhist[t]);
    __syncthreads();

    // pass 2 (chunk re-read is L2-warm)
    for (long e0 = start; e0 < end; e0 += blockDim.x) {
        long e = e0 + t;
        bool valid = e < end;
        int src = 0, dst = 0, myr = 8;
        if (valid) {
            src = load_src(ei, e, E, f64);
            dst = load_dst(ei, e, E, f64);
            myr = (int)((float)dst * inv8);
            myr = myr > 7 ? 7 : myr;
        }
        unsigned long long mym = 0;
        int mypos = 0;
        #pragma unroll
        for (int r = 0; r < 8; r++) {
            unsigned long long mr = __ballot(myr == r);
            int cnt = __popcll(mr);
            int b = 0;
            if (lane == r && cnt) b = atomicAdd(&lcur[r], cnt);   // LDS alloc
            b = __shfl(b, r);
            if (myr == r) { mym = mr; mypos = b; }
        }
        if (valid) {
            int rank = __popcll(mym & ((1ull << lane) - 1));
            part[(long)myr * partCap + lbase[myr] + mypos + rank] = make_int2(src, dst);
        }
    }
}

__global__ void scan_block_kernel(const int* __restrict__ in, int* __restrict__ excl,
                                  int* __restrict__ bsums, int N) {
    __shared__ int s[256];
    int t = threadIdx.x;
    int gid = blockIdx.x * 256 + t;
    int v = (gid < N) ? in[gid] : 0;
    s[t] = v;
    __syncthreads();
    #pragma unroll
    for (int d = 1; d < 256; d <<= 1) {
        int tv = (t >= d) ? s[t - d] : 0;
        __syncthreads();
        s[t] += tv;
        __syncthreads();
    }
    if (gid < N) excl[gid] = s[t] - v;
    if (t == 255 && bsums) bsums[blockIdx.x] = s[255];
}

__global__ void scan_finalize_kernel(const int* __restrict__ counts, int* __restrict__ off,
                                     const int* __restrict__ bsums, int* __restrict__ cursor,
                                     float* __restrict__ dinv, int N, int E) {
    int gid = blockIdx.x * 256 + threadIdx.x;
    if (gid < N) {
        int o = off[gid] + bsums[blockIdx.x];
        off[gid] = o;
        cursor[gid] = o;
        dinv[gid] = 1.0f / sqrtf((float)(counts[gid] + 1));
    }
    if (gid == 0) off[N] = E;
}

// ---- Scatter: XCD-confined; range r = blockIdx&7 ---------------------------
__global__ void scatter_kernel(const int2* __restrict__ part, long partCap,
                               const int* __restrict__ pcur, int* __restrict__ cursor,
                               int* __restrict__ col) {
    int r = blockIdx.x & 7;
    int n = pcur[r * PCUR_STRIDE];
    const int2* p = part + (long)r * partCap;
    int i = (blockIdx.x >> 3) * blockDim.x + threadIdx.x;
    int stride = (gridDim.x >> 3) * blockDim.x;
    for (; i < n; i += stride) {
        int2 sd = p[i];
        int pos = atomicAdd(&cursor[sd.y], 1);
        col[pos] = sd.x;
    }
}

// ---- W1 [512,128] f32 -> Bt [128][512] bf16 (n-major, k-contiguous) --------
__global__ void w1bt_kernel(const float* __restrict__ W1, unsigned short* __restrict__ Bt) {
    int n = blockIdx.x;
    for (int k = threadIdx.x; k < FEAT1; k += blockDim.x)
        Bt[(long)n * FEAT1 + k] = f2bf(W1[(long)k * FEAT2 + n]);
}

// ---- W2 [128,40] f32 -> Bt2 [48][128] bf16 (n-major, k-contiguous, 0-pad) --
__global__ void w2bt_kernel(const float* __restrict__ W2, unsigned short* __restrict__ Bt2) {
    int n = blockIdx.x;            // 0..47
    for (int k = threadIdx.x; k < FEAT2; k += blockDim.x)
        Bt2[(long)n * FEAT2 + k] = (n < FEAT3) ? f2bf(W2[(long)k * FEAT3 + n]) : 0;
}

// ---- GEMM1 (MFMA): [M,512]f32 x Bt[128][512]bf16 -> h1s bf16, *dinv[row] ---
__launch_bounds__(256)
__global__ void gemm1_mfma_kernel(const float* __restrict__ A,
                                  const unsigned short* __restrict__ Bt,
                                  const float* __restrict__ dinv,
                                  unsigned short* __restrict__ C, int M) {
    __shared__ uint4 Asm[256];          // 64 rows x 32 k bf16, fragment order
    int t = threadIdx.x;
    int m0 = blockIdx.x * 64;
    int w = t >> 6, lane = t & 63;
    int wr = w >> 1, wc = w & 1;
    int quad = lane >> 4, r15 = lane & 15;

    f32x4 acc[2][4];
    #pragma unroll
    for (int mt = 0; mt < 2; mt++)
        #pragma unroll
        for (int nt = 0; nt < 4; nt++) acc[mt][nt] = (f32x4){0.f, 0.f, 0.f, 0.f};

    for (int k0 = 0; k0 < FEAT1; k0 += 32) {
        __syncthreads();
        #pragma unroll
        for (int i = 0; i < 2; i++) {
            int id = t + i * 256;
            int row = id >> 3, q = id & 7;
            int grow = m0 + row;
            float4 v = make_float4(0.f, 0.f, 0.f, 0.f);
            if (grow < M) v = *(const float4*)(A + (long)grow * FEAT1 + k0 + q * 4);
            uint2 p;
            p.x = (unsigned)f2bf(v.x) | ((unsigned)f2bf(v.y) << 16);
            p.y = (unsigned)f2bf(v.z) | ((unsigned)f2bf(v.w) << 16);
            ((uint2*)Asm)[(row >> 4) * 128 + (((row & 15) + ((q >> 1) << 4)) << 1) + (q & 1)] = p;
        }
        __syncthreads();

        bf16x8 af[2];
        #pragma unroll
        for (int mt = 0; mt < 2; mt++)
            af[mt] = ((const bf16x8*)Asm)[(wr * 2 + mt) * 64 + lane];

        #pragma unroll
        for (int nt = 0; nt < 4; nt++) {
            bf16x8 bf = *(const bf16x8*)(Bt + (long)(wc * 64 + nt * 16 + r15) * FEAT1 + k0 + quad * 8);
            acc[0][nt] = __builtin_amdgcn_mfma_f32_16x16x32_bf16(af[0], bf, acc[0][nt], 0, 0, 0);
            acc[1][nt] = __builtin_amdgcn_mfma_f32_16x16x32_bf16(af[1], bf, acc[1][nt], 0, 0, 0);
        }
    }

    #pragma unroll
    for (int mt = 0; mt < 2; mt++) {
        int rb = m0 + wr * 32 + mt * 16 + quad * 4;
        #pragma unroll
        for (int reg = 0; reg < 4; reg++) {
            int row = rb + reg;
            if (row >= M) continue;
            float di = dinv[row];
            #pragma unroll
            for (int nt = 0; nt < 4; nt++) {
                C[(long)row * FEAT2 + wc * 64 + nt * 16 + r15] = f2bf(acc[mt][nt][reg] * di);
            }
        }
    }
}

// ---- Aggregation 1: wave-per-node; shfl-broadcast col; writes bf16 a1 -------
__launch_bounds__(256)
__global__ void agg1_kernel(const unsigned short* __restrict__ h1s,
                            const int* __restrict__ col, const int* __restrict__ off,
                            const float* __restrict__ dinv, const float* __restrict__ b1,
                            unsigned short* __restrict__ a1, int N) {
    int node = blockIdx.x * 4 + (threadIdx.x >> 6);
    if (node >= N) return;
    int l = threadIdx.x & 63;            // lane handles feats 2l, 2l+1
    int o0 = off[node], o1 = off[node + 1];
    float ax = 0.f, ay = 0.f;
    for (int base = o0; base < o1; base += 64) {
        int cnt = min(64, o1 - base);
        int myc = (l < cnt) ? col[base + l] : 0;
        int e = 0;
        for (; e + 4 <= cnt; e += 4) {
            int s0 = __shfl(myc, e + 0);
            int s1 = __shfl(myc, e + 1);
            int s2 = __shfl(myc, e + 2);
            int s3 = __shfl(myc, e + 3);
            unsigned p0 = *(const unsigned*)(h1s + (long)s0 * FEAT2 + 2 * l);
            unsigned p1 = *(const unsigned*)(h1s + (long)s1 * FEAT2 + 2 * l);
            unsigned p2 = *(const unsigned*)(h1s + (long)s2 * FEAT2 + 2 * l);
            unsigned p3 = *(const unsigned*)(h1s + (long)s3 * FEAT2 + 2 * l);
            ax += bf2f(p0 & 0xffffu) + bf2f(p1 & 0xffffu) +
                  bf2f(p2 & 0xffffu) + bf2f(p3 & 0xffffu);
            ay += bf2f(p0 >> 16) + bf2f(p1 >> 16) + bf2f(p2 >> 16) + bf2f(p3 >> 16);
        }
        for (; e < cnt; ++e) {
            int s = __shfl(myc, e);
            unsigned p = *(const unsigned*)(h1s + (long)s * FEAT2 + 2 * l);
            ax += bf2f(p & 0xffffu);
            ay += bf2f(p >> 16);
        }
    }
    unsigned pv = *(const unsigned*)(h1s + (long)node * FEAT2 + 2 * l);  // self
    ax += bf2f(pv & 0xffffu);
    ay += bf2f(pv >> 16);
    float di = dinv[node];
    float2 b = *(const float2*)(b1 + 2 * l);
    float vx = ax * di + b.x;
    float vy = ay * di + b.y;
    vx = vx > 0.f ? vx : 0.f;
    vy = vy > 0.f ? vy : 0.f;
    *(unsigned*)(a1 + (long)node * FEAT2 + 2 * l) =
        (unsigned)f2bf(vx) | ((unsigned)f2bf(vy) << 16);
}

// ---- GEMM2 (MFMA): a1[M,128]bf16 x Bt2[48][128]bf16 -> h2s bf16, *dinv -----
// One wave per 16 rows; 4 k-steps x 3 n-tiles of 16x16x32. No LDS.
__launch_bounds__(256)
__global__ void gemm2_mfma_kernel(const unsigned short* __restrict__ A,
                                  const unsigned short* __restrict__ Bt2,
                                  const float* __restrict__ dinv,
                                  unsigned short* __restrict__ C, int M) {
    int wave = blockIdx.x * (blockDim.x >> 6) + (threadIdx.x >> 6);
    int lane = threadIdx.x & 63;
    int quad = lane >> 4, r15 = lane & 15;
    int row0 = wave * 16;
    if (row0 >= M) return;
    int arow = row0 + r15;
    if (arow >= M) arow = M - 1;         // clamp: A row m only affects C row m

    bf16x8 af[4];
    const unsigned short* ap = A + (long)arow * FEAT2 + quad * 8;
    #pragma unroll
    for (int ks = 0; ks < 4; ks++) af[ks] = *(const bf16x8*)(ap + ks * 32);

    f32x4 acc[3];
    #pragma unroll
    for (int nt = 0; nt < 3; nt++) acc[nt] = (f32x4){0.f, 0.f, 0.f, 0.f};
    #pragma unroll
    for (int ks = 0; ks < 4; ks++) {
        #pragma unroll
        for (int nt = 0; nt < 3; nt++) {
            bf16x8 bf = *(const bf16x8*)(Bt2 + (long)(nt * 16 + r15) * FEAT2 + ks * 32 + quad * 8);
            acc[nt] = __builtin_amdgcn_mfma_f32_16x16x32_bf16(af[ks], bf, acc[nt], 0, 0, 0);
        }
    }

    // C/D: col=lane&15, row=quad*4+reg
    #pragma unroll
    for (int reg = 0; reg < 4; reg++) {
        int orow = row0 + quad * 4 + reg;
        if (orow >= M) continue;
        float di = dinv[orow];
        #pragma unroll
        for (int nt = 0; nt < 3; nt++) {
            int ocol = nt * 16 + r15;
            if (ocol < FEAT3)
                C[(long)orow * FEAT3 + ocol] = f2bf(acc[nt][reg] * di);
        }
    }
}

// ---- Aggregation 2 + log_softmax: wave-per-node, shfl col, 4-way unroll -----
__launch_bounds__(256)
__global__ void agg2_lsm_kernel(const unsigned short* __restrict__ h2s,
                                const int* __restrict__ col, const int* __restrict__ off,
                                const float* __restrict__ dinv, const float* __restrict__ b2,
                                float* __restrict__ out, int N) {
    int node = blockIdx.x * 4 + (threadIdx.x >> 6);
    if (node >= N) return;
    int l = threadIdx.x & 63;
    bool act = l < FEAT3 / 2;
    int o0 = off[node], o1 = off[node + 1];
    float ax = 0.f, ay = 0.f;
    for (int base = o0; base < o1; base += 64) {
        int cnt = min(64, o1 - base);
        int myc = (l < cnt) ? col[base + l] : 0;
        int e = 0;
        for (; e + 4 <= cnt; e += 4) {
            int s0 = __shfl(myc, e + 0);
            int s1 = __shfl(myc, e + 1);
            int s2 = __shfl(myc, e + 2);
            int s3 = __shfl(myc, e + 3);
            if (act) {
                unsigned p0 = *(const unsigned*)(h2s + (long)s0 * FEAT3 + 2 * l);
                unsigned p1 = *(const unsigned*)(h2s + (long)s1 * FEAT3 + 2 * l);
                unsigned p2 = *(const unsigned*)(h2s + (long)s2 * FEAT3 + 2 * l);
                unsigned p3 = *(const unsigned*)(h2s + (long)s3 * FEAT3 + 2 * l);
                ax += bf2f(p0 & 0xffffu) + bf2f(p1 & 0xffffu) +
                      bf2f(p2 & 0xffffu) + bf2f(p3 & 0xffffu);
                ay += bf2f(p0 >> 16) + bf2f(p1 >> 16) + bf2f(p2 >> 16) + bf2f(p3 >> 16);
            }
        }
        for (; e < cnt; ++e) {
            int s = __shfl(myc, e);
            if (act) {
                unsigned p = *(const unsigned*)(h2s + (long)s * FEAT3 + 2 * l);
                ax += bf2f(p & 0xffffu);
                ay += bf2f(p >> 16);
            }
        }
    }
    float vx = -INFINITY, vy = -INFINITY;
    if (act) {
        unsigned pv = *(const unsigned*)(h2s + (long)node * FEAT3 + 2 * l);  // self
        float di = dinv[node];
        float2 b = *(const float2*)(b2 + 2 * l);
        vx = (ax + bf2f(pv & 0xffffu)) * di + b.x;
        vy = (ay + bf2f(pv >> 16)) * di + b.y;
    }
    float m = fmaxf(vx, vy);
    #pragma unroll
    for (int o = 32; o >= 1; o >>= 1) m = fmaxf(m, __shfl_xor(m, o));
    float e = act ? (expf(vx - m) + expf(vy - m)) : 0.f;
    #pragma unroll
    for (int o = 32; o >= 1; o >>= 1) e += __shfl_xor(e, o);
    float ls = logf(e);
    if (act) {
        *(float2*)(out + (long)node * FEAT3 + 2 * l) = make_float2(vx - m - ls, vy - m - ls);
    }
}

// ---------------------------------------------------------------------------
extern "C" void kernel_launch(void* const* d_in, const int* in_sizes, int n_in,
                              void* d_out, int out_size, void* d_ws, size_t ws_size,
                              hipStream_t stream) {
    const float* x  = (const float*)d_in[0];
    const int*   ei = (const int*)d_in[1];
    const float* W1 = (const float*)d_in[2];
    const float* b1 = (const float*)d_in[3];
    const float* W2 = (const float*)d_in[4];
    const float* b2 = (const float*)d_in[5];
    float* out = (float*)d_out;

    const int  N = in_sizes[0] / FEAT1;       // 50000
    const long E = in_sizes[1] / 2;           // 1600000

    char* ws = (char*)d_ws;
    size_t off = 0;
    auto alloc = [&](size_t bytes) -> void* {
        off = (off + 255) & ~(size_t)255;
        void* p = ws + off;
        off += bytes;
        return p;
    };
    const long partCap = E / 8 + 65536;
    int*   counts  = (int*)alloc((size_t)N * 4);
    int*   offsets = (int*)alloc((size_t)(N + 1) * 4);
    int*   cursor  = (int*)alloc((size_t)N * 4);
    float* dinv    = (float*)alloc((size_t)N * 4);
    int*   col     = (int*)alloc((size_t)E * 4);
    unsigned short* h1s = (unsigned short*)alloc((size_t)N * FEAT2 * 2);
    unsigned short* a1  = (unsigned short*)alloc((size_t)N * FEAT2 * 2);
    unsigned short* h2s = (unsigned short*)alloc((size_t)N * FEAT3 * 2);
    unsigned short* Bt  = (unsigned short*)alloc((size_t)FEAT2 * FEAT1 * 2);
    unsigned short* Bt2 = (unsigned short*)alloc((size_t)48 * FEAT2 * 2);
    int2*  part    = (int2*)alloc((size_t)8 * partCap * 8);
    int*   pcur    = (int*)alloc(8 * PCUR_STRIDE * 4);
    int*   bsums   = (int*)alloc(256 * 4);
    int*   flagp   = (int*)alloc(4);

    const int nb = (N + 255) / 256;

    detect_i64_kernel<<<1, 256, 0, stream>>>(ei, flagp);
    hipMemsetAsync(counts, 0, (size_t)N * 4, stream);
    hipMemsetAsync(pcur, 0, (size_t)8 * PCUR_STRIDE * 4, stream);
    part_kernel<<<256, 1024, 0, stream>>>(ei, flagp, counts, pcur, part, partCap,
                                          E, 8.0f / (float)N);
    scan_block_kernel<<<nb, 256, 0, stream>>>(counts, offsets, bsums, N);
    scan_block_kernel<<<1, 256, 0, stream>>>(bsums, bsums, nullptr, nb);
    scan_finalize_kernel<<<nb, 256, 0, stream>>>(counts, offsets, bsums, cursor, dinv, N, (int)E);
    scatter_kernel<<<2048, 256, 0, stream>>>(part, partCap, pcur, cursor, col);

    w1bt_kernel<<<FEAT2, 256, 0, stream>>>(W1, Bt);
    w2bt_kernel<<<48, 128, 0, stream>>>(W2, Bt2);
    gemm1_mfma_kernel<<<(N + 63) / 64, 256, 0, stream>>>(x, Bt, dinv, h1s, N);
    agg1_kernel<<<(N + 3) / 4, 256, 0, stream>>>(h1s, col, offsets, dinv, b1, a1, N);
    gemm2_mfma_kernel<<<(N / 16 + 3) / 4, 256, 0, stream>>>(a1, Bt2, dinv, h2s, N);
    agg2_lsm_kernel<<<(N + 3) / 4, 256, 0, stream>>>(h2s, col, offsets, dinv, b2, out, N);
}

// Round 8
// 344.705 us; speedup vs baseline: 8.0302x; 1.3298x over previous
//
#include <hip/hip_runtime.h>
#include <hip/hip_bf16.h>
#include <math.h>

// ---------------------------------------------------------------------------
// GCN 2-layer. A_hat = D^-1/2 (A+I) D^-1/2 factored: scale GEMM rows by dinv
// (epilogue), gather-sum neighbors, scale by dinv[dst], add self term.
// Round 8: CSR build with ZERO per-edge global atomics (each random global
// atomic costs ~32B memory-side traffic; 1.6M in part + 1.6M in scatter were
// ~100MB hidden WRITE traffic). Two-level counting sort:
//   partA: bucket by dst>>8 (196 buckets x 256 nodes), LDS hist + one global
//          claim per bucket per block; edges packed to 4B (src | dlocal<<17).
//   bscan: 196-entry prefix -> bucket bases.
//   partB: per-bucket LDS degree hist + scan -> offsets/dinv directly; LDS
//          cursor scatter -> col (contiguous 32KB window, full lines).
// ---------------------------------------------------------------------------

#define FEAT1 512
#define FEAT2 128
#define FEAT3 40

typedef __attribute__((ext_vector_type(8))) short bf16x8;
typedef __attribute__((ext_vector_type(4))) float f32x4;

__device__ __forceinline__ unsigned short f2bf(float f) {
    union { float f; unsigned u; } c; c.f = f;
    unsigned r = c.u + 0x7fff + ((c.u >> 16) & 1);   // round-nearest-even
    return (unsigned short)(r >> 16);
}
__device__ __forceinline__ float bf2f(unsigned v16) {
    union { unsigned u; float f; } c; c.u = v16 << 16;
    return c.f;
}

// ---- edge_index may be int32 (JAX default) or int64. -----------------------
__global__ void detect_i64_kernel(const int* __restrict__ ei, int* flagp) {
    __shared__ int any;
    if (threadIdx.x == 0) any = 0;
    __syncthreads();
    int v = ei[2 * threadIdx.x + 1];
    if (v != 0) any = 1;
    __syncthreads();
    if (threadIdx.x == 0) *flagp = (any == 0) ? 1 : 0;   // 1 => int64 layout
}

__device__ __forceinline__ int load_src(const int* ei, long e, long E, int f64) {
    return f64 ? ei[2 * e] : ei[e];
}
__device__ __forceinline__ int load_dst(const int* ei, long e, long E, int f64) {
    return f64 ? ei[2 * E + 2 * e] : ei[E + e];
}

// ---- partA: bucket edges by dst>>8; LDS hist; 1 global claim/bucket/block --
__launch_bounds__(1024)
__global__ void partA_kernel(const int* __restrict__ ei, const int* __restrict__ flagp,
                             int* __restrict__ gbkt, unsigned* __restrict__ part,
                             int bktCap, long E, int NB) {
    __shared__ int hist[256], lbase[256], lcur[256];
    int f64 = *flagp;
    int t = threadIdx.x;
    long chunk = (E + gridDim.x - 1) / gridDim.x;
    long start = (long)blockIdx.x * chunk;
    long end = start + chunk; if (end > E) end = E;
    if (t < 256) { hist[t] = 0; lcur[t] = 0; }
    __syncthreads();

    for (long e0 = start; e0 < end; e0 += 1024) {
        long e = e0 + t;
        if (e < end) {
            int dst = load_dst(ei, e, E, f64);
            atomicAdd(&hist[dst >> 8], 1);
        }
    }
    __syncthreads();
    if (t < NB && hist[t]) lbase[t] = atomicAdd(&gbkt[t], hist[t]);
    __syncthreads();

    for (long e0 = start; e0 < end; e0 += 1024) {
        long e = e0 + t;
        if (e < end) {
            int src = load_src(ei, e, E, f64);
            int dst = load_dst(ei, e, E, f64);
            int bkt = dst >> 8;
            int pos = lbase[bkt] + atomicAdd(&lcur[bkt], 1);
            if (pos < bktCap)
                part[(long)bkt * bktCap + pos] = (unsigned)src | ((unsigned)(dst & 255) << 17);
        }
    }
}

// ---- bscan: exclusive prefix over bucket totals ----------------------------
__global__ void bscan_kernel(const int* __restrict__ gbkt, int* __restrict__ bktBase,
                             int* __restrict__ offsets, int NB, int N, int E) {
    __shared__ int s[256];
    int t = threadIdx.x;
    int v = (t < NB) ? gbkt[t] : 0;
    s[t] = v;
    __syncthreads();
    #pragma unroll
    for (int d = 1; d < 256; d <<= 1) {
        int tv = (t >= d) ? s[t - d] : 0;
        __syncthreads();
        s[t] += tv;
        __syncthreads();
    }
    bktBase[t] = s[t] - v;
    if (t == 0) offsets[N] = E;
}

// ---- partB: per-bucket degree hist + scan -> offsets/dinv; scatter col -----
__launch_bounds__(256)
__global__ void partB_kernel(const unsigned* __restrict__ part, int bktCap,
                             const int* __restrict__ gbkt, const int* __restrict__ bktBase,
                             int* __restrict__ offsets, float* __restrict__ dinv,
                             int* __restrict__ col, int N) {
    __shared__ int h[256], sc[256], cur[256];
    int b = blockIdx.x, t = threadIdx.x;
    int n = gbkt[b]; if (n > bktCap) n = bktCap;
    int base = bktBase[b];
    int lo = b << 8;
    const unsigned* p = part + (long)b * bktCap;
    h[t] = 0;
    __syncthreads();
    for (int i = t; i < n; i += 256) atomicAdd(&h[(p[i] >> 17) & 255], 1);
    __syncthreads();
    int cnt = h[t];
    sc[t] = cnt;
    __syncthreads();
    #pragma unroll
    for (int d = 1; d < 256; d <<= 1) {
        int tv = (t >= d) ? sc[t - d] : 0;
        __syncthreads();
        sc[t] += tv;
        __syncthreads();
    }
    int ex = sc[t] - cnt;
    int node = lo + t;
    if (node < N) {
        offsets[node] = base + ex;
        dinv[node] = 1.0f / sqrtf((float)(cnt + 1));   // +1 self-loop
    }
    cur[t] = ex;
    __syncthreads();
    for (int i = t; i < n; i += 256) {
        unsigned u = p[i];
        int r = atomicAdd(&cur[(u >> 17) & 255], 1);
        col[base + r] = u & 0x1FFFF;
    }
}

// ---- W1 [512,128] f32 -> Bt [128][512] bf16 (n-major, k-contiguous) --------
__global__ void w1bt_kernel(const float* __restrict__ W1, unsigned short* __restrict__ Bt) {
    int n = blockIdx.x;
    for (int k = threadIdx.x; k < FEAT1; k += blockDim.x)
        Bt[(long)n * FEAT1 + k] = f2bf(W1[(long)k * FEAT2 + n]);
}

// ---- W2 [128,40] f32 -> Bt2 [48][128] bf16 (n-major, k-contiguous, 0-pad) --
__global__ void w2bt_kernel(const float* __restrict__ W2, unsigned short* __restrict__ Bt2) {
    int n = blockIdx.x;            // 0..47
    for (int k = threadIdx.x; k < FEAT2; k += blockDim.x)
        Bt2[(long)n * FEAT2 + k] = (n < FEAT3) ? f2bf(W2[(long)k * FEAT3 + n]) : 0;
}

// ---- GEMM1 (MFMA): [M,512]f32 x Bt[128][512]bf16 -> h1s bf16, *dinv[row] ---
__launch_bounds__(256)
__global__ void gemm1_mfma_kernel(const float* __restrict__ A,
                                  const unsigned short* __restrict__ Bt,
                                  const float* __restrict__ dinv,
                                  unsigned short* __restrict__ C, int M) {
    __shared__ uint4 Asm[256];          // 64 rows x 32 k bf16, fragment order
    int t = threadIdx.x;
    int m0 = blockIdx.x * 64;
    int w = t >> 6, lane = t & 63;
    int wr = w >> 1, wc = w & 1;
    int quad = lane >> 4, r15 = lane & 15;

    f32x4 acc[2][4];
    #pragma unroll
    for (int mt = 0; mt < 2; mt++)
        #pragma unroll
        for (int nt = 0; nt < 4; nt++) acc[mt][nt] = (f32x4){0.f, 0.f, 0.f, 0.f};

    for (int k0 = 0; k0 < FEAT1; k0 += 32) {
        __syncthreads();
        #pragma unroll
        for (int i = 0; i < 2; i++) {
            int id = t + i * 256;
            int row = id >> 3, q = id & 7;
            int grow = m0 + row;
            float4 v = make_float4(0.f, 0.f, 0.f, 0.f);
            if (grow < M) v = *(const float4*)(A + (long)grow * FEAT1 + k0 + q * 4);
            uint2 p;
            p.x = (unsigned)f2bf(v.x) | ((unsigned)f2bf(v.y) << 16);
            p.y = (unsigned)f2bf(v.z) | ((unsigned)f2bf(v.w) << 16);
            ((uint2*)Asm)[(row >> 4) * 128 + (((row & 15) + ((q >> 1) << 4)) << 1) + (q & 1)] = p;
        }
        __syncthreads();

        bf16x8 af[2];
        #pragma unroll
        for (int mt = 0; mt < 2; mt++)
            af[mt] = ((const bf16x8*)Asm)[(wr * 2 + mt) * 64 + lane];

        #pragma unroll
        for (int nt = 0; nt < 4; nt++) {
            bf16x8 bf = *(const bf16x8*)(Bt + (long)(wc * 64 + nt * 16 + r15) * FEAT1 + k0 + quad * 8);
            acc[0][nt] = __builtin_amdgcn_mfma_f32_16x16x32_bf16(af[0], bf, acc[0][nt], 0, 0, 0);
            acc[1][nt] = __builtin_amdgcn_mfma_f32_16x16x32_bf16(af[1], bf, acc[1][nt], 0, 0, 0);
        }
    }

    #pragma unroll
    for (int mt = 0; mt < 2; mt++) {
        int rb = m0 + wr * 32 + mt * 16 + quad * 4;
        #pragma unroll
        for (int reg = 0; reg < 4; reg++) {
            int row = rb + reg;
            if (row >= M) continue;
            float di = dinv[row];
            #pragma unroll
            for (int nt = 0; nt < 4; nt++) {
                C[(long)row * FEAT2 + wc * 64 + nt * 16 + r15] = f2bf(acc[mt][nt][reg] * di);
            }
        }
    }
}

// ---- Aggregation 1: wave-per-node; shfl-broadcast col; writes bf16 a1 -------
__launch_bounds__(256)
__global__ void agg1_kernel(const unsigned short* __restrict__ h1s,
                            const int* __restrict__ col, const int* __restrict__ off,
                            const float* __restrict__ dinv, const float* __restrict__ b1,
                            unsigned short* __restrict__ a1, int N) {
    int node = blockIdx.x * 4 + (threadIdx.x >> 6);
    if (node >= N) return;
    int l = threadIdx.x & 63;            // lane handles feats 2l, 2l+1
    int o0 = off[node], o1 = off[node + 1];
    float ax = 0.f, ay = 0.f;
    for (int base = o0; base < o1; base += 64) {
        int cnt = min(64, o1 - base);
        int myc = (l < cnt) ? col[base + l] : 0;
        int e = 0;
        for (; e + 4 <= cnt; e += 4) {
            int s0 = __shfl(myc, e + 0);
            int s1 = __shfl(myc, e + 1);
            int s2 = __shfl(myc, e + 2);
            int s3 = __shfl(myc, e + 3);
            unsigned p0 = *(const unsigned*)(h1s + (long)s0 * FEAT2 + 2 * l);
            unsigned p1 = *(const unsigned*)(h1s + (long)s1 * FEAT2 + 2 * l);
            unsigned p2 = *(const unsigned*)(h1s + (long)s2 * FEAT2 + 2 * l);
            unsigned p3 = *(const unsigned*)(h1s + (long)s3 * FEAT2 + 2 * l);
            ax += bf2f(p0 & 0xffffu) + bf2f(p1 & 0xffffu) +
                  bf2f(p2 & 0xffffu) + bf2f(p3 & 0xffffu);
            ay += bf2f(p0 >> 16) + bf2f(p1 >> 16) + bf2f(p2 >> 16) + bf2f(p3 >> 16);
        }
        for (; e < cnt; ++e) {
            int s = __shfl(myc, e);
            unsigned p = *(const unsigned*)(h1s + (long)s * FEAT2 + 2 * l);
            ax += bf2f(p & 0xffffu);
            ay += bf2f(p >> 16);
        }
    }
    unsigned pv = *(const unsigned*)(h1s + (long)node * FEAT2 + 2 * l);  // self
    ax += bf2f(pv & 0xffffu);
    ay += bf2f(pv >> 16);
    float di = dinv[node];
    float2 b = *(const float2*)(b1 + 2 * l);
    float vx = ax * di + b.x;
    float vy = ay * di + b.y;
    vx = vx > 0.f ? vx : 0.f;
    vy = vy > 0.f ? vy : 0.f;
    *(unsigned*)(a1 + (long)node * FEAT2 + 2 * l) =
        (unsigned)f2bf(vx) | ((unsigned)f2bf(vy) << 16);
}

// ---- GEMM2 (MFMA): a1[M,128]bf16 x Bt2[48][128]bf16 -> h2s bf16, *dinv -----
__launch_bounds__(256)
__global__ void gemm2_mfma_kernel(const unsigned short* __restrict__ A,
                                  const unsigned short* __restrict__ Bt2,
                                  const float* __restrict__ dinv,
                                  unsigned short* __restrict__ C, int M) {
    int wave = blockIdx.x * (blockDim.x >> 6) + (threadIdx.x >> 6);
    int lane = threadIdx.x & 63;
    int quad = lane >> 4, r15 = lane & 15;
    int row0 = wave * 16;
    if (row0 >= M) return;
    int arow = row0 + r15;
    if (arow >= M) arow = M - 1;         // clamp: A row m only affects C row m

    bf16x8 af[4];
    const unsigned short* ap = A + (long)arow * FEAT2 + quad * 8;
    #pragma unroll
    for (int ks = 0; ks < 4; ks++) af[ks] = *(const bf16x8*)(ap + ks * 32);

    f32x4 acc[3];
    #pragma unroll
    for (int nt = 0; nt < 3; nt++) acc[nt] = (f32x4){0.f, 0.f, 0.f, 0.f};
    #pragma unroll
    for (int ks = 0; ks < 4; ks++) {
        #pragma unroll
        for (int nt = 0; nt < 3; nt++) {
            bf16x8 bf = *(const bf16x8*)(Bt2 + (long)(nt * 16 + r15) * FEAT2 + ks * 32 + quad * 8);
            acc[nt] = __builtin_amdgcn_mfma_f32_16x16x32_bf16(af[ks], bf, acc[nt], 0, 0, 0);
        }
    }

    // C/D: col=lane&15, row=quad*4+reg
    #pragma unroll
    for (int reg = 0; reg < 4; reg++) {
        int orow = row0 + quad * 4 + reg;
        if (orow >= M) continue;
        float di = dinv[orow];
        #pragma unroll
        for (int nt = 0; nt < 3; nt++) {
            int ocol = nt * 16 + r15;
            if (ocol < FEAT3)
                C[(long)orow * FEAT3 + ocol] = f2bf(acc[nt][reg] * di);
        }
    }
}

// ---- Aggregation 2 + log_softmax: wave-per-node, shfl col, 4-way unroll -----
__launch_bounds__(256)
__global__ void agg2_lsm_kernel(const unsigned short* __restrict__ h2s,
                                const int* __restrict__ col, const int* __restrict__ off,
                                const float* __restrict__ dinv, const float* __restrict__ b2,
                                float* __restrict__ out, int N) {
    int node = blockIdx.x * 4 + (threadIdx.x >> 6);
    if (node >= N) return;
    int l = threadIdx.x & 63;
    bool act = l < FEAT3 / 2;
    int o0 = off[node], o1 = off[node + 1];
    float ax = 0.f, ay = 0.f;
    for (int base = o0; base < o1; base += 64) {
        int cnt = min(64, o1 - base);
        int myc = (l < cnt) ? col[base + l] : 0;
        int e = 0;
        for (; e + 4 <= cnt; e += 4) {
            int s0 = __shfl(myc, e + 0);
            int s1 = __shfl(myc, e + 1);
            int s2 = __shfl(myc, e + 2);
            int s3 = __shfl(myc, e + 3);
            if (act) {
                unsigned p0 = *(const unsigned*)(h2s + (long)s0 * FEAT3 + 2 * l);
                unsigned p1 = *(const unsigned*)(h2s + (long)s1 * FEAT3 + 2 * l);
                unsigned p2 = *(const unsigned*)(h2s + (long)s2 * FEAT3 + 2 * l);
                unsigned p3 = *(const unsigned*)(h2s + (long)s3 * FEAT3 + 2 * l);
                ax += bf2f(p0 & 0xffffu) + bf2f(p1 & 0xffffu) +
                      bf2f(p2 & 0xffffu) + bf2f(p3 & 0xffffu);
                ay += bf2f(p0 >> 16) + bf2f(p1 >> 16) + bf2f(p2 >> 16) + bf2f(p3 >> 16);
            }
        }
        for (; e < cnt; ++e) {
            int s = __shfl(myc, e);
            if (act) {
                unsigned p = *(const unsigned*)(h2s + (long)s * FEAT3 + 2 * l);
                ax += bf2f(p & 0xffffu);
                ay += bf2f(p >> 16);
            }
        }
    }
    float vx = -INFINITY, vy = -INFINITY;
    if (act) {
        unsigned pv = *(const unsigned*)(h2s + (long)node * FEAT3 + 2 * l);  // self
        float di = dinv[node];
        float2 b = *(const float2*)(b2 + 2 * l);
        vx = (ax + bf2f(pv & 0xffffu)) * di + b.x;
        vy = (ay + bf2f(pv >> 16)) * di + b.y;
    }
    float m = fmaxf(vx, vy);
    #pragma unroll
    for (int o = 32; o >= 1; o >>= 1) m = fmaxf(m, __shfl_xor(m, o));
    float e = act ? (expf(vx - m) + expf(vy - m)) : 0.f;
    #pragma unroll
    for (int o = 32; o >= 1; o >>= 1) e += __shfl_xor(e, o);
    float ls = logf(e);
    if (act) {
        *(float2*)(out + (long)node * FEAT3 + 2 * l) = make_float2(vx - m - ls, vy - m - ls);
    }
}

// ---------------------------------------------------------------------------
extern "C" void kernel_launch(void* const* d_in, const int* in_sizes, int n_in,
                              void* d_out, int out_size, void* d_ws, size_t ws_size,
                              hipStream_t stream) {
    const float* x  = (const float*)d_in[0];
    const int*   ei = (const int*)d_in[1];
    const float* W1 = (const float*)d_in[2];
    const float* b1 = (const float*)d_in[3];
    const float* W2 = (const float*)d_in[4];
    const float* b2 = (const float*)d_in[5];
    float* out = (float*)d_out;

    const int  N = in_sizes[0] / FEAT1;       // 50000
    const long E = in_sizes[1] / 2;           // 1600000

    char* ws = (char*)d_ws;
    size_t off = 0;
    auto alloc = [&](size_t bytes) -> void* {
        off = (off + 255) & ~(size_t)255;
        void* p = ws + off;
        off += bytes;
        return p;
    };
    const int NB = (N + 255) >> 8;            // 196 buckets of 256 nodes
    const int bktCap = (int)(E / NB) + 1024;  // mean + >>10 sigma slack
    int*   offsets = (int*)alloc((size_t)(N + 1) * 4);
    float* dinv    = (float*)alloc((size_t)N * 4);
    int*   col     = (int*)alloc((size_t)E * 4);
    unsigned short* h1s = (unsigned short*)alloc((size_t)N * FEAT2 * 2);
    unsigned short* a1  = (unsigned short*)alloc((size_t)N * FEAT2 * 2);
    unsigned short* h2s = (unsigned short*)alloc((size_t)N * FEAT3 * 2);
    unsigned short* Bt  = (unsigned short*)alloc((size_t)FEAT2 * FEAT1 * 2);
    unsigned short* Bt2 = (unsigned short*)alloc((size_t)48 * FEAT2 * 2);
    unsigned* part = (unsigned*)alloc((size_t)NB * bktCap * 4);
    int*   gbkt    = (int*)alloc(256 * 4);
    int*   bktBase = (int*)alloc(256 * 4);
    int*   flagp   = (int*)alloc(4);

    detect_i64_kernel<<<1, 256, 0, stream>>>(ei, flagp);
    hipMemsetAsync(gbkt, 0, 256 * 4, stream);
    partA_kernel<<<256, 1024, 0, stream>>>(ei, flagp, gbkt, part, bktCap, E, NB);
    bscan_kernel<<<1, 256, 0, stream>>>(gbkt, bktBase, offsets, NB, N, (int)E);
    partB_kernel<<<NB, 256, 0, stream>>>(part, bktCap, gbkt, bktBase, offsets, dinv, col, N);

    w1bt_kernel<<<FEAT2, 256, 0, stream>>>(W1, Bt);
    w2bt_kernel<<<48, 128, 0, stream>>>(W2, Bt2);
    gemm1_mfma_kernel<<<(N + 63) / 64, 256, 0, stream>>>(x, Bt, dinv, h1s, N);
    agg1_kernel<<<(N + 3) / 4, 256, 0, stream>>>(h1s, col, offsets, dinv, b1, a1, N);
    gemm2_mfma_kernel<<<(N / 16 + 3) / 4, 256, 0, stream>>>(a1, Bt2, dinv, h2s, N);
    agg2_lsm_kernel<<<(N + 3) / 4, 256, 0, stream>>>(h2s, col, offsets, dinv, b2, out, N);
}